// Round 2
// baseline (1207.737 us; speedup 1.0000x reference)
//
#include <hip/hip_runtime.h>

typedef _Float16 v8h __attribute__((ext_vector_type(8)));
typedef _Float16 v4h __attribute__((ext_vector_type(4)));
typedef float    v4f __attribute__((ext_vector_type(4)));

#define GK 6432      // true K / N of the big GEMM
#define GN 6432
#define GM 2048
#define KP 6528      // K padded to 102*64 for BK=64 pipeline

// ---------------------------------------------------------------------------
// Weight conversion: wl fp32 [6432,6432] -> fp16 [6432, KP], K-pad cols zeroed
// ---------------------------------------------------------------------------
__global__ void convert_w(const float* __restrict__ wl, _Float16* __restrict__ Wh)
{
    const int row = blockIdx.y;                       // 0..6431
    const int col = (blockIdx.x * 256 + threadIdx.x) * 4;
    if (col >= KP) return;
    v4h h;
    if (col < GK) {
        const float4 f = *(const float4*)(wl + (long)row * GK + col);
        h[0] = (_Float16)f.x; h[1] = (_Float16)f.y;
        h[2] = (_Float16)f.z; h[3] = (_Float16)f.w;
    } else {
        h[0] = (_Float16)0.f; h[1] = (_Float16)0.f;
        h[2] = (_Float16)0.f; h[3] = (_Float16)0.f;
    }
    *(v4h*)(Wh + (long)row * KP + col) = h;
}

// ---------------------------------------------------------------------------
// Multi-scale conv feature extractor (unchanged). F0 [2048, KP] fp16.
// ---------------------------------------------------------------------------
#define SX   0
#define SX2  2048
#define SX4  3136
#define SW1  3712
#define SB1  4032
#define SW2  4048
#define SB2  6608
#define SP1  6640
#define LDSZ 13808

__global__ __launch_bounds__(256) void conv_feat(
    const float* __restrict__ x,
    const float* __restrict__ w1, const float* __restrict__ b1,
    const float* __restrict__ w2, const float* __restrict__ b2,
    _Float16* __restrict__ F0)
{
    __shared__ float lds[LDSZ];
    const int tid = threadIdx.x;
    const long b  = blockIdx.x;

    for (int i = tid; i < 1920; i += 256) {
        int c = i / 480, t = i % 480;
        lds[SX + c * 512 + t] = x[(b * 4 + c) * 480 + t];
    }
    for (int i = tid; i < 320;  i += 256) lds[SW1 + i] = w1[i];
    for (int i = tid; i < 16;   i += 256) lds[SB1 + i] = b1[i];
    for (int i = tid; i < 2560; i += 256) lds[SW2 + i] = w2[i];
    for (int i = tid; i < 32;   i += 256) lds[SB2 + i] = b2[i];
    for (int i = tid; i < KP - GK; i += 256) F0[b * KP + GK + i] = (_Float16)0.f;
    __syncthreads();

    for (int i = tid; i < 960; i += 256) {
        int c = i / 240, t = i % 240;
        lds[SX2 + c * 272 + t] = 0.5f * (lds[SX + c * 512 + 2 * t] + lds[SX + c * 512 + 2 * t + 1]);
    }
    for (int i = tid; i < 480; i += 256) {
        int c = i / 120, t = i % 120;
        float s = lds[SX + c * 512 + 4 * t]     + lds[SX + c * 512 + 4 * t + 1]
                + lds[SX + c * 512 + 4 * t + 2] + lds[SX + c * 512 + 4 * t + 3];
        lds[SX4 + c * 144 + t] = 0.25f * s;
    }
    __syncthreads();

    for (int jid = tid; jid < 16 * 34; jid += 256) {
        const int c1 = jid / 34, rid = jid % 34;
        const int sidx = (rid < 19) ? 0 : (rid < 29 ? 1 : 2);
        const int r0   = (sidx == 0) ? rid : (sidx == 1 ? rid - 19 : rid - 29);
        const int u0   = r0 * 13;
        const int xbase  = (sidx == 0) ? SX  : (sidx == 1 ? SX2 : SX4);
        const int xpitch = (sidx == 0) ? 512 : (sidx == 1 ? 272 : 144);
        const int P      = (sidx == 0) ? 238 : (sidx == 1 ? 118 : 58);
        const int pofs   = (sidx == 0) ? 0   : (sidx == 1 ? 238 : 356);

        float acc[26];
        const float bias = lds[SB1 + c1];
        #pragma unroll
        for (int i = 0; i < 26; ++i) acc[i] = bias;

        #pragma unroll
        for (int ci = 0; ci < 4; ++ci) {
            float w[30];
            const float* xr = &lds[xbase + ci * xpitch + 2 * u0];
            #pragma unroll
            for (int q = 0; q < 15; ++q) {
                float2 t2 = *(const float2*)(xr + 2 * q);
                w[2 * q] = t2.x; w[2 * q + 1] = t2.y;
            }
            float wt[5];
            #pragma unroll
            for (int k = 0; k < 5; ++k) wt[k] = lds[SW1 + (c1 * 4 + ci) * 5 + k];
            #pragma unroll
            for (int i = 0; i < 26; ++i) {
                #pragma unroll
                for (int k = 0; k < 5; ++k) acc[i] += w[i + k] * wt[k];
            }
        }
        #pragma unroll
        for (int i = 0; i < 13; ++i) {
            int u = u0 + i;
            if (u < P)
                lds[SP1 + c1 * 448 + pofs + u] = fmaxf(fmaxf(acc[2 * i], acc[2 * i + 1]), 0.f);
        }
    }
    __syncthreads();

    for (int jid = tid; jid < 32 * 17; jid += 256) {
        const int c2 = jid / 17, rid = jid % 17;
        const int sidx = (rid < 9) ? 0 : (rid < 14 ? 1 : 2);
        const int r0   = (sidx == 0) ? rid : (sidx == 1 ? rid - 9 : rid - 14);
        const int v0   = r0 * 13;
        const int pbase = (sidx == 0) ? 0   : (sidx == 1 ? 238 : 356);
        const int Pv    = (sidx == 0) ? 117 : (sidx == 1 ? 57  : 27);
        const int vout  = (sidx == 0) ? 0   : (sidx == 1 ? 117 : 174);

        float acc[26];
        const float bias = lds[SB2 + c2];
        #pragma unroll
        for (int i = 0; i < 26; ++i) acc[i] = bias;

        for (int c1 = 0; c1 < 16; ++c1) {
            float w[30];
            const float* pr = &lds[SP1 + c1 * 448 + pbase + 2 * v0];
            #pragma unroll
            for (int q = 0; q < 15; ++q) {
                float2 t2 = *(const float2*)(pr + 2 * q);
                w[2 * q] = t2.x; w[2 * q + 1] = t2.y;
            }
            float wt[5];
            #pragma unroll
            for (int k = 0; k < 5; ++k) wt[k] = lds[SW2 + (c2 * 16 + c1) * 5 + k];
            #pragma unroll
            for (int i = 0; i < 26; ++i) {
                #pragma unroll
                for (int k = 0; k < 5; ++k) acc[i] += w[i + k] * wt[k];
            }
        }
        #pragma unroll
        for (int i = 0; i < 13; ++i) {
            int v = v0 + i;
            if (v < Pv) {
                float f = fmaxf(fmaxf(acc[2 * i], acc[2 * i + 1]), 0.f);
                F0[b * KP + c2 * 201 + vout + v] = (_Float16)f;
            }
        }
    }
}

// ---------------------------------------------------------------------------
// 256x256x(BK=64) 8-phase NT GEMM, self-staged rebalanced schedule.
// 8 waves (2M x 4N), per-wave 128x64. ds_read per phase: 8/4/8/4 (was 12/4/8/0).
//
// Self-staging: wave (wr,wc) stages A rows [wr*128+wc*32,+32) and B rows
// [wc*64+wr*32,+32) -- the B set is EXACTLY its own bf_self fragment rows,
// so its own vmcnt suffices to read-ahead bf_self for the next round after
// the counted vmcnt(8), before the closing barrier (no cross-wave race:
// stage sets are disjoint).
// Per-wave MFMA quadrant order: (mh0,self),(mh0,other),(mh1,other),(mh1,self)
// where self = n-half wr. accS/accO arrays statically indexed (rule #20).
// Stage placement (region free-time proven by phase barriers):
//   P2: A-h0 set (wc<2 waves)   -- A-h0 last read at P1
//   P3: B self (all waves)      -- B last read at P2
//   P4: A-h1 set (wc>=2 waves)  -- A-h1 last read at P3
// vmcnt(8) once per round (8 = this round's own stages), never 0 mid-loop.
// Stage addressing: precomputed clamped row pointers, +=128 elems per pair.
// ---------------------------------------------------------------------------
__global__ __launch_bounds__(512, 2) void gemm8(
    const _Float16* __restrict__ A, const _Float16* __restrict__ Bw,
    const float* __restrict__ bias, _Float16* __restrict__ C)
{
    __shared__ _Float16 sA[2][256 * 64];   // 32 KB per buf
    __shared__ _Float16 sB[2][256 * 64];   // total 128 KB

    const int tid  = threadIdx.x;
    const int lane = tid & 63;
    const int wave = tid >> 6;
    const int wr   = wave >> 2;          // m-half
    const int wc   = wave & 3;           // n-quarter

    const int id  = blockIdx.x;          // 208 = 8 m-tiles x 26 n-tiles
    const long tile_m = (long)(id & 7) << 8;   // XCD-affine: A strip L2-resident
    const long tile_n = (long)(id >> 3) << 8;

    // ---- staging geometry (linear LDS dst = uniform base + lane*16B) ----
    const int lrow = lane >> 3;
    const int lcol = ((lane & 7) ^ lrow) << 3;   // pre-XOR-swizzled source col

    const int arow = wr * 128 + wc * 32;         // A self rows [arow, +32)
    const int brow = wc * 64 + wr * 32;          // B self rows [brow, +32)
    const _Float16* pA = A + (tile_m + arow + lrow) * (long)KP + lcol;
    long br0 = tile_n + brow + lrow;
    long br1 = br0 + 8, br2 = br0 + 16, br3 = br0 + 24;
    if (br0 > 6431) br0 = 6431;                  // last n-tile row clamp:
    if (br1 > 6431) br1 = 6431;                  // garbage feeds only cols the
    if (br2 > 6431) br2 = 6431;                  // epilogue discards/zeroes
    if (br3 > 6431) br3 = 6431;
    const _Float16* pB0 = Bw + br0 * (long)KP + lcol;
    const _Float16* pB1 = Bw + br1 * (long)KP + lcol;
    const _Float16* pB2 = Bw + br2 * (long)KP + lcol;
    const _Float16* pB3 = Bw + br3 * (long)KP + lcol;

    const int aDst = arow * 64;
    const int bDst = brow * 64;

#define GLD(p, d) __builtin_amdgcn_global_load_lds(                          \
        (const __attribute__((address_space(1))) void*)(p),                  \
        (__attribute__((address_space(3))) void*)(d), 16, 0, 0)

#define STAGE_A4(SBUF, KO) {                                                 \
    GLD(pA + (KO),            &sA[SBUF][aDst]);                              \
    GLD(pA + (KO) +  8L * KP, &sA[SBUF][aDst +  512]);                       \
    GLD(pA + (KO) + 16L * KP, &sA[SBUF][aDst + 1024]);                       \
    GLD(pA + (KO) + 24L * KP, &sA[SBUF][aDst + 1536]); }

#define STAGE_B4(SBUF, KO) {                                                 \
    GLD(pB0 + (KO), &sB[SBUF][bDst]);                                        \
    GLD(pB1 + (KO), &sB[SBUF][bDst +  512]);                                 \
    GLD(pB2 + (KO), &sB[SBUF][bDst + 1024]);                                 \
    GLD(pB3 + (KO), &sB[SBUF][bDst + 1536]); }

    // ---- fragment read geometry (swizzled ds_read_b128) ----
    const int fr = lane & 15;
    const int fp = lane >> 4;
    const int sw = fr & 7;
    const int slot0 = ((fp)     ^ sw) << 3;
    const int slot1 = ((fp + 4) ^ sw) << 3;
    const int abase = (wr * 128 + fr) * 64;
    const int boffS = (wc * 64 + fr) * 64 + wr * 2048;        // self n-half
    const int boffO = (wc * 64 + fr) * 64 + (1 - wr) * 2048;  // other n-half

    v8h af[4][2], bfO[2][2], bfs0[2][2], bfs1[2][2];
    v4f accS[8][2], accO[8][2];
    #pragma unroll
    for (int m = 0; m < 8; ++m) {
        #pragma unroll
        for (int ni = 0; ni < 2; ++ni) {
            v4f z = {0.f, 0.f, 0.f, 0.f};
            accS[m][ni] = z; accO[m][ni] = z;
        }
    }

#define LDA(CA, H) { _Pragma("unroll")                                       \
    for (int mi = 0; mi < 4; ++mi) {                                         \
        af[mi][0] = *(const v8h*)&(CA)[abase + (H) * 4096 + mi * 1024 + slot0]; \
        af[mi][1] = *(const v8h*)&(CA)[abase + (H) * 4096 + mi * 1024 + slot1]; \
    } }

#define LDBF(CB, BOFF, D) {                                                  \
    D[0][0] = *(const v8h*)&(CB)[(BOFF) + slot0];                            \
    D[0][1] = *(const v8h*)&(CB)[(BOFF) + slot1];                            \
    D[1][0] = *(const v8h*)&(CB)[(BOFF) + 1024 + slot0];                     \
    D[1][1] = *(const v8h*)&(CB)[(BOFF) + 1024 + slot1]; }

#define MMAQ(ACC, MH, BF) { _Pragma("unroll")                                \
    for (int mi = 0; mi < 4; ++mi) { _Pragma("unroll")                       \
        for (int ni = 0; ni < 2; ++ni) {                                     \
            ACC[(MH)*4+mi][ni] = __builtin_amdgcn_mfma_f32_16x16x32_f16(     \
                af[mi][0], BF[ni][0], ACC[(MH)*4+mi][ni], 0, 0, 0);          \
            ACC[(MH)*4+mi][ni] = __builtin_amdgcn_mfma_f32_16x16x32_f16(     \
                af[mi][1], BF[ni][1], ACC[(MH)*4+mi][ni], 0, 0, 0);          \
        } } }

#define ROUND(CA, CB, CBN, SBUF, KO, BFS, BFSN, S2, RA) {                    \
    /* P1: af(h0); MFMA (mh0, self) */                                       \
    LDA(CA, 0);                                                              \
    __builtin_amdgcn_s_barrier();                                            \
    asm volatile("s_waitcnt lgkmcnt(0)" ::: "memory");                       \
    __builtin_amdgcn_s_setprio(1);                                           \
    MMAQ(accS, 0, BFS);                                                      \
    __builtin_amdgcn_s_setprio(0);                                           \
    __builtin_amdgcn_s_barrier();                                            \
    /* P2: bf(other); stage A-h0 (wc<2); MFMA (mh0, other) */                \
    LDBF(CB, boffO, bfO);                                                    \
    if ((S2) && wc < 2) STAGE_A4(SBUF, KO);                                  \
    __builtin_amdgcn_s_barrier();                                            \
    asm volatile("s_waitcnt lgkmcnt(0)" ::: "memory");                       \
    __builtin_amdgcn_s_setprio(1);                                           \
    MMAQ(accO, 0, bfO);                                                      \
    __builtin_amdgcn_s_setprio(0);                                           \
    __builtin_amdgcn_s_barrier();                                            \
    /* P3: af(h1); stage B self; MFMA (mh1, other) */                        \
    LDA(CA, 1);                                                              \
    if (S2) STAGE_B4(SBUF, KO);                                              \
    __builtin_amdgcn_s_barrier();                                            \
    asm volatile("s_waitcnt lgkmcnt(0)" ::: "memory");                       \
    __builtin_amdgcn_s_setprio(1);                                           \
    MMAQ(accO, 1, bfO);                                                      \
    __builtin_amdgcn_s_setprio(0);                                           \
    __builtin_amdgcn_s_barrier();                                            \
    /* P4: stage A-h1 (wc>=2); MFMA (mh1, self); counted vmcnt; read-ahead */\
    if ((S2) && wc >= 2) STAGE_A4(SBUF, KO);                                 \
    __builtin_amdgcn_s_barrier();                                            \
    __builtin_amdgcn_s_setprio(1);                                           \
    MMAQ(accS, 1, BFS);                                                      \
    __builtin_amdgcn_s_setprio(0);                                           \
    if (S2) { asm volatile("s_waitcnt vmcnt(8)" ::: "memory"); }             \
    else    { asm volatile("s_waitcnt vmcnt(0)" ::: "memory"); }             \
    if (RA) LDBF(CBN, boffS, BFSN);                                          \
    __builtin_amdgcn_sched_barrier(0);                                       \
    __builtin_amdgcn_s_barrier(); }

    // ---- prologue: stage tile0->buf0, tile1->buf1; read-ahead bf_self(t0)
    STAGE_A4(0, 0);  STAGE_B4(0, 0);
    STAGE_A4(1, 64); STAGE_B4(1, 64);
    pA += 128; pB0 += 128; pB1 += 128; pB2 += 128; pB3 += 128;
    asm volatile("s_waitcnt vmcnt(8)" ::: "memory");   // tile0's 8 landed
    __builtin_amdgcn_s_barrier();
    LDBF(sB[0], boffS, bfs0);

    for (int kt = 0; kt < 102; kt += 2) {
        const bool s2a = kt < 100;
        const bool s2b = kt < 99;          // (kt+1) < 100
        const bool raB = kt < 100;         // (kt+1) < 101
        ROUND(sA[0], sB[0], sB[1], 0, 0,  bfs0, bfs1, s2a, true);
        ROUND(sA[1], sB[1], sB[0], 1, 64, bfs1, bfs0, s2b, raB);
        pA += 128; pB0 += 128; pB1 += 128; pB2 += 128; pB3 += 128;
    }

    // ---- epilogue: C/D layout col=lane&15, row=(lane>>4)*4+reg ----
#define EPI(ACC, COL0) { _Pragma("unroll")                                   \
    for (int ni = 0; ni < 2; ++ni) {                                         \
        const long col = (COL0) + ni * 16;                                   \
        if (col < KP) {                                                      \
            const bool val = col < GN;                                       \
            const float bv = val ? bias[col] : 0.f;                          \
            _Pragma("unroll")                                                \
            for (int m = 0; m < 8; ++m) {                                    \
                const long row = tile_m + wr * 128 + m * 16 + fp * 4;        \
                _Pragma("unroll")                                            \
                for (int r = 0; r < 4; ++r) {                                \
                    float v = ACC[m][ni][r] + bv;                            \
                    v = v > 0.f ? v : 0.f;                                   \
                    C[(row + r) * (long)KP + col] = val ? (_Float16)v        \
                                                        : (_Float16)0.f;     \
                }                                                            \
            }                                                                \
        }                                                                    \
    } }

    const long colS0 = tile_n + wc * 64 + wr * 32 + fr;
    const long colO0 = tile_n + wc * 64 + (1 - wr) * 32 + fr;
    EPI(accS, colS0);
    EPI(accO, colO0);

#undef GLD
#undef STAGE_A4
#undef STAGE_B4
#undef LDA
#undef LDBF
#undef MMAQ
#undef ROUND
#undef EPI
}

// ---------------------------------------------------------------------------
// Final projection: out[b,o] = sum_k F[b,k]*wo[o,k] + bo[o].
// ---------------------------------------------------------------------------
__global__ __launch_bounds__(256) void final_out(
    const _Float16* __restrict__ F, const float* __restrict__ wo,
    const float* __restrict__ bo, float* __restrict__ out)
{
    __shared__ float red[4][8];
    const long b   = blockIdx.x;
    const int tid  = threadIdx.x;
    const int lane = tid & 63;
    const int wave = tid >> 6;
    float acc[5] = {0.f, 0.f, 0.f, 0.f, 0.f};
    const _Float16* f = F + b * KP;

    const int c1 = (wave + 1) * 402;
    for (int c = wave * 402 + lane; c < c1; c += 64) {
        const int k = c << 2;
        v4h f4 = *(const v4h*)(f + k);
        const float f0 = (float)f4[0], f1 = (float)f4[1];
        const float f2 = (float)f4[2], f3 = (float)f4[3];
        #pragma unroll
        for (int o = 0; o < 5; ++o) {
            const float4 w4 = *(const float4*)(wo + o * GK + k);
            acc[o] += f0 * w4.x + f1 * w4.y + f2 * w4.z + f3 * w4.w;
        }
    }
    #pragma unroll
    for (int o = 0; o < 5; ++o) {
        #pragma unroll
        for (int off = 32; off > 0; off >>= 1) acc[o] += __shfl_down(acc[o], off, 64);
    }
    if (lane == 0) {
        #pragma unroll
        for (int o = 0; o < 5; ++o) red[wave][o] = acc[o];
    }
    __syncthreads();
    if (tid < 5)
        out[b * 5 + tid] = red[0][tid] + red[1][tid] + red[2][tid] + red[3][tid] + bo[tid];
}

// ---------------------------------------------------------------------------
extern "C" void kernel_launch(void* const* d_in, const int* in_sizes, int n_in,
                              void* d_out, int out_size, void* d_ws, size_t ws_size,
                              hipStream_t stream)
{
    const float* x  = (const float*)d_in[0];
    const float* w1 = (const float*)d_in[1];
    const float* b1 = (const float*)d_in[2];
    const float* w2 = (const float*)d_in[3];
    const float* b2 = (const float*)d_in[4];
    const float* wl = (const float*)d_in[5];
    const float* bl = (const float*)d_in[6];
    const float* wo = (const float*)d_in[7];
    const float* bo = (const float*)d_in[8];
    float* out = (float*)d_out;

    char* ws = (char*)d_ws;
    _Float16* Wh = (_Float16*)ws;                                   // 6432*6528*2 = 83,976,192 B
    _Float16* F0 = (_Float16*)(ws + 83976192);                      // 2048*6528*2 = 26,738,688 B
    _Float16* F1 = (_Float16*)(ws + 83976192 + 26738688);

    convert_w<<<dim3(7, GN), 256, 0, stream>>>(wl, Wh);
    conv_feat<<<GM, 256, 0, stream>>>(x, w1, b1, w2, b2, F0);
    gemm8<<<208, 512, 0, stream>>>(F0, Wh, bl, F1);
    gemm8<<<208, 512, 0, stream>>>(F1, Wh, bl, F0);
    gemm8<<<208, 512, 0, stream>>>(F0, Wh, bl, F1);
    gemm8<<<208, 512, 0, stream>>>(F1, Wh, bl, F0);
    final_out<<<GM, 256, 0, stream>>>(F0, wo, bo, out);
}

// Round 3
// 1176.273 us; speedup vs baseline: 1.0267x; 1.0267x over previous
//
#include <hip/hip_runtime.h>

typedef _Float16 v8h  __attribute__((ext_vector_type(8)));
typedef _Float16 v4h  __attribute__((ext_vector_type(4)));
typedef float    f32x16 __attribute__((ext_vector_type(16)));

#define GK 6432      // true K / N of the big GEMM
#define GN 6432
#define GM 2048
#define KP 6528      // K padded to 102*64 for BK=64 pipeline

// ---------------------------------------------------------------------------
// Weight conversion: wl fp32 [6432,6432] -> fp16 [6432, KP], K-pad cols zeroed
// ---------------------------------------------------------------------------
__global__ void convert_w(const float* __restrict__ wl, _Float16* __restrict__ Wh)
{
    const int row = blockIdx.y;                       // 0..6431
    const int col = (blockIdx.x * 256 + threadIdx.x) * 4;
    if (col >= KP) return;
    v4h h;
    if (col < GK) {
        const float4 f = *(const float4*)(wl + (long)row * GK + col);
        h[0] = (_Float16)f.x; h[1] = (_Float16)f.y;
        h[2] = (_Float16)f.z; h[3] = (_Float16)f.w;
    } else {
        h[0] = (_Float16)0.f; h[1] = (_Float16)0.f;
        h[2] = (_Float16)0.f; h[3] = (_Float16)0.f;
    }
    *(v4h*)(Wh + (long)row * KP + col) = h;
}

// ---------------------------------------------------------------------------
// Multi-scale conv feature extractor (unchanged). F0 [2048, KP] fp16.
// ---------------------------------------------------------------------------
#define SX   0
#define SX2  2048
#define SX4  3136
#define SW1  3712
#define SB1  4032
#define SW2  4048
#define SB2  6608
#define SP1  6640
#define LDSZ 13808

__global__ __launch_bounds__(256) void conv_feat(
    const float* __restrict__ x,
    const float* __restrict__ w1, const float* __restrict__ b1,
    const float* __restrict__ w2, const float* __restrict__ b2,
    _Float16* __restrict__ F0)
{
    __shared__ float lds[LDSZ];
    const int tid = threadIdx.x;
    const long b  = blockIdx.x;

    for (int i = tid; i < 1920; i += 256) {
        int c = i / 480, t = i % 480;
        lds[SX + c * 512 + t] = x[(b * 4 + c) * 480 + t];
    }
    for (int i = tid; i < 320;  i += 256) lds[SW1 + i] = w1[i];
    for (int i = tid; i < 16;   i += 256) lds[SB1 + i] = b1[i];
    for (int i = tid; i < 2560; i += 256) lds[SW2 + i] = w2[i];
    for (int i = tid; i < 32;   i += 256) lds[SB2 + i] = b2[i];
    for (int i = tid; i < KP - GK; i += 256) F0[b * KP + GK + i] = (_Float16)0.f;
    __syncthreads();

    for (int i = tid; i < 960; i += 256) {
        int c = i / 240, t = i % 240;
        lds[SX2 + c * 272 + t] = 0.5f * (lds[SX + c * 512 + 2 * t] + lds[SX + c * 512 + 2 * t + 1]);
    }
    for (int i = tid; i < 480; i += 256) {
        int c = i / 120, t = i % 120;
        float s = lds[SX + c * 512 + 4 * t]     + lds[SX + c * 512 + 4 * t + 1]
                + lds[SX + c * 512 + 4 * t + 2] + lds[SX + c * 512 + 4 * t + 3];
        lds[SX4 + c * 144 + t] = 0.25f * s;
    }
    __syncthreads();

    for (int jid = tid; jid < 16 * 34; jid += 256) {
        const int c1 = jid / 34, rid = jid % 34;
        const int sidx = (rid < 19) ? 0 : (rid < 29 ? 1 : 2);
        const int r0   = (sidx == 0) ? rid : (sidx == 1 ? rid - 19 : rid - 29);
        const int u0   = r0 * 13;
        const int xbase  = (sidx == 0) ? SX  : (sidx == 1 ? SX2 : SX4);
        const int xpitch = (sidx == 0) ? 512 : (sidx == 1 ? 272 : 144);
        const int P      = (sidx == 0) ? 238 : (sidx == 1 ? 118 : 58);
        const int pofs   = (sidx == 0) ? 0   : (sidx == 1 ? 238 : 356);

        float acc[26];
        const float bias = lds[SB1 + c1];
        #pragma unroll
        for (int i = 0; i < 26; ++i) acc[i] = bias;

        #pragma unroll
        for (int ci = 0; ci < 4; ++ci) {
            float w[30];
            const float* xr = &lds[xbase + ci * xpitch + 2 * u0];
            #pragma unroll
            for (int q = 0; q < 15; ++q) {
                float2 t2 = *(const float2*)(xr + 2 * q);
                w[2 * q] = t2.x; w[2 * q + 1] = t2.y;
            }
            float wt[5];
            #pragma unroll
            for (int k = 0; k < 5; ++k) wt[k] = lds[SW1 + (c1 * 4 + ci) * 5 + k];
            #pragma unroll
            for (int i = 0; i < 26; ++i) {
                #pragma unroll
                for (int k = 0; k < 5; ++k) acc[i] += w[i + k] * wt[k];
            }
        }
        #pragma unroll
        for (int i = 0; i < 13; ++i) {
            int u = u0 + i;
            if (u < P)
                lds[SP1 + c1 * 448 + pofs + u] = fmaxf(fmaxf(acc[2 * i], acc[2 * i + 1]), 0.f);
        }
    }
    __syncthreads();

    for (int jid = tid; jid < 32 * 17; jid += 256) {
        const int c2 = jid / 17, rid = jid % 17;
        const int sidx = (rid < 9) ? 0 : (rid < 14 ? 1 : 2);
        const int r0   = (sidx == 0) ? rid : (sidx == 1 ? rid - 9 : rid - 14);
        const int v0   = r0 * 13;
        const int pbase = (sidx == 0) ? 0   : (sidx == 1 ? 238 : 356);
        const int Pv    = (sidx == 0) ? 117 : (sidx == 1 ? 57  : 27);
        const int vout  = (sidx == 0) ? 0   : (sidx == 1 ? 117 : 174);

        float acc[26];
        const float bias = lds[SB2 + c2];
        #pragma unroll
        for (int i = 0; i < 26; ++i) acc[i] = bias;

        for (int c1 = 0; c1 < 16; ++c1) {
            float w[30];
            const float* pr = &lds[SP1 + c1 * 448 + pbase + 2 * v0];
            #pragma unroll
            for (int q = 0; q < 15; ++q) {
                float2 t2 = *(const float2*)(pr + 2 * q);
                w[2 * q] = t2.x; w[2 * q + 1] = t2.y;
            }
            float wt[5];
            #pragma unroll
            for (int k = 0; k < 5; ++k) wt[k] = lds[SW2 + (c2 * 16 + c1) * 5 + k];
            #pragma unroll
            for (int i = 0; i < 26; ++i) {
                #pragma unroll
                for (int k = 0; k < 5; ++k) acc[i] += w[i + k] * wt[k];
            }
        }
        #pragma unroll
        for (int i = 0; i < 13; ++i) {
            int v = v0 + i;
            if (v < Pv) {
                float f = fmaxf(fmaxf(acc[2 * i], acc[2 * i + 1]), 0.f);
                F0[b * KP + c2 * 201 + vout + v] = (_Float16)f;
            }
        }
    }
}

// ---------------------------------------------------------------------------
// 256x256x(BK=64) NT GEMM, R2 staging/sync skeleton UNCHANGED; MFMA shape
// switched 16x16x32 -> 32x32x16 (half the instructions, 2x work each --
// attacks the latency-bound MFMA issue at 2 waves/SIMD).
// Wave tile 128x64 = 4 m-frags x 2 n-frags of 32x32. 4 phases/round, each
// phase = 2 m-frags x 1 n-frag x full K=64 (4 k-slices) = 8 MFMA.
// Fragment mapping (32x32x16 f16, 4 A/B regs): lane l supplies
// A[row=l&31][k=8*(l>>5)..+8] -> one v8h ds_read_b128 per (frag, slice).
// C/D: col=lane&31, row=(reg&3)+8*(reg>>2)+4*(lane>>5)   [m74/m101].
// Staging regions, phase read-order, vmcnt(8), swizzle: identical to R2.
// ---------------------------------------------------------------------------
__global__ __launch_bounds__(512, 2) void gemm8(
    const _Float16* __restrict__ A, const _Float16* __restrict__ Bw,
    const float* __restrict__ bias, _Float16* __restrict__ C)
{
    __shared__ _Float16 sA[2][256 * 64];   // 32 KB per buf
    __shared__ _Float16 sB[2][256 * 64];   // total 128 KB

    const int tid  = threadIdx.x;
    const int lane = tid & 63;
    const int wave = tid >> 6;
    const int wr   = wave >> 2;          // m-half
    const int wc   = wave & 3;           // n-quarter

    const int id  = blockIdx.x;          // 208 = 8 m-tiles x 26 n-tiles
    const long tile_m = (long)(id & 7) << 8;   // m-fastest: chunked-dispatch L2 reuse
    const long tile_n = (long)(id >> 3) << 8;

    // ---- staging geometry (linear LDS dst = uniform base + lane*16B) ----
    const int lrow = lane >> 3;
    const int lcol = ((lane & 7) ^ lrow) << 3;   // pre-XOR-swizzled source col

    const int arow = wr * 128 + wc * 32;         // A self rows [arow, +32)
    const int brow = wc * 64 + wr * 32;          // B self rows [brow, +32)
    const _Float16* pA = A + (tile_m + arow + lrow) * (long)KP + lcol;
    long br0 = tile_n + brow + lrow;
    long br1 = br0 + 8, br2 = br0 + 16, br3 = br0 + 24;
    if (br0 > 6431) br0 = 6431;                  // last n-tile row clamp
    if (br1 > 6431) br1 = 6431;
    if (br2 > 6431) br2 = 6431;
    if (br3 > 6431) br3 = 6431;
    const _Float16* pB0 = Bw + br0 * (long)KP + lcol;
    const _Float16* pB1 = Bw + br1 * (long)KP + lcol;
    const _Float16* pB2 = Bw + br2 * (long)KP + lcol;
    const _Float16* pB3 = Bw + br3 * (long)KP + lcol;

    const int aDst = arow * 64;
    const int bDst = brow * 64;

#define GLD(p, d) __builtin_amdgcn_global_load_lds(                          \
        (const __attribute__((address_space(1))) void*)(p),                  \
        (__attribute__((address_space(3))) void*)(d), 16, 0, 0)

#define STAGE_A4(SBUF, KO) {                                                 \
    GLD(pA + (KO),            &sA[SBUF][aDst]);                              \
    GLD(pA + (KO) +  8L * KP, &sA[SBUF][aDst +  512]);                       \
    GLD(pA + (KO) + 16L * KP, &sA[SBUF][aDst + 1024]);                       \
    GLD(pA + (KO) + 24L * KP, &sA[SBUF][aDst + 1536]); }

#define STAGE_B4(SBUF, KO) {                                                 \
    GLD(pB0 + (KO), &sB[SBUF][bDst]);                                        \
    GLD(pB1 + (KO), &sB[SBUF][bDst +  512]);                                 \
    GLD(pB2 + (KO), &sB[SBUF][bDst + 1024]);                                 \
    GLD(pB3 + (KO), &sB[SBUF][bDst + 1536]); }

    // ---- fragment read geometry (swizzled ds_read_b128, 32x32x16) ----
    const int fr32 = lane & 31;                  // frag row/col
    const int g    = lane >> 5;                  // k-group 0..1
    const int sw8  = lane & 7;                   // row&7 (bases are x32)
    int q8[4];
    #pragma unroll
    for (int s = 0; s < 4; ++s) q8[s] = (((2 * s + g) ^ sw8) << 3);

    const int bS = wc * 64 + wr * 32;            // self  n-frag row base
    const int bO = wc * 64 + (1 - wr) * 32;      // other n-frag row base

    v8h af[2][4], bfS[4], bfO[4];
    f32x16 accS[4], accO[4];
    #pragma unroll
    for (int f = 0; f < 4; ++f) {
        #pragma unroll
        for (int r = 0; r < 16; ++r) { accS[f][r] = 0.f; accO[f][r] = 0.f; }
    }

#define LDA(CA, H) { _Pragma("unroll")                                       \
    for (int j = 0; j < 2; ++j) { _Pragma("unroll")                          \
        for (int s = 0; s < 4; ++s)                                          \
            af[j][s] = *(const v8h*)&(CA)[(wr * 128 + ((H) * 2 + j) * 32 + fr32) * 64 + q8[s]]; \
    } }

#define LDBF(CB, BROW, D) { _Pragma("unroll")                                \
    for (int s = 0; s < 4; ++s)                                              \
        D[s] = *(const v8h*)&(CB)[((BROW) + fr32) * 64 + q8[s]]; }

#define MMAP(A0, A1, BF) { _Pragma("unroll")                                 \
    for (int s = 0; s < 4; ++s) {                                            \
        A0 = __builtin_amdgcn_mfma_f32_32x32x16_f16(af[0][s], BF[s], A0, 0, 0, 0); \
        A1 = __builtin_amdgcn_mfma_f32_32x32x16_f16(af[1][s], BF[s], A1, 0, 0, 0); \
    } }

#define ROUND(CA, CB, SBUF, KO, S2) {                                        \
    /* P1: A-frags 0,1 + B-self; MFMA (m01, self) */                         \
    LDBF(CB, bS, bfS); LDA(CA, 0);                                           \
    __builtin_amdgcn_s_barrier();                                            \
    asm volatile("s_waitcnt lgkmcnt(0)" ::: "memory");                       \
    __builtin_amdgcn_s_setprio(1);                                           \
    MMAP(accS[0], accS[1], bfS);                                             \
    __builtin_amdgcn_s_setprio(0);                                           \
    __builtin_amdgcn_s_barrier();                                            \
    /* P2: B-other; stage A-h0 (wc<2); MFMA (m01, other) */                  \
    LDBF(CB, bO, bfO);                                                       \
    if ((S2) && wc < 2) STAGE_A4(SBUF, KO);                                  \
    __builtin_amdgcn_s_barrier();                                            \
    asm volatile("s_waitcnt lgkmcnt(0)" ::: "memory");                       \
    __builtin_amdgcn_s_setprio(1);                                           \
    MMAP(accO[0], accO[1], bfO);                                             \
    __builtin_amdgcn_s_setprio(0);                                           \
    __builtin_amdgcn_s_barrier();                                            \
    /* P3: A-frags 2,3; stage B self; MFMA (m23, other) */                   \
    LDA(CA, 1);                                                              \
    if (S2) STAGE_B4(SBUF, KO);                                              \
    __builtin_amdgcn_s_barrier();                                            \
    asm volatile("s_waitcnt lgkmcnt(0)" ::: "memory");                       \
    __builtin_amdgcn_s_setprio(1);                                           \
    MMAP(accO[2], accO[3], bfO);                                             \
    __builtin_amdgcn_s_setprio(0);                                           \
    __builtin_amdgcn_s_barrier();                                            \
    /* P4: stage A-h1 (wc>=2); MFMA (m23, self); counted vmcnt */            \
    if ((S2) && wc >= 2) STAGE_A4(SBUF, KO);                                 \
    __builtin_amdgcn_s_barrier();                                            \
    __builtin_amdgcn_s_setprio(1);                                           \
    MMAP(accS[2], accS[3], bfS);                                             \
    __builtin_amdgcn_s_setprio(0);                                           \
    if (S2) { asm volatile("s_waitcnt vmcnt(8)" ::: "memory"); }             \
    else    { asm volatile("s_waitcnt vmcnt(0)" ::: "memory"); }             \
    __builtin_amdgcn_s_barrier(); }

    // ---- prologue: stage tile0->buf0, tile1->buf1 ----
    STAGE_A4(0, 0);  STAGE_B4(0, 0);
    STAGE_A4(1, 64); STAGE_B4(1, 64);
    pA += 128; pB0 += 128; pB1 += 128; pB2 += 128; pB3 += 128;
    asm volatile("s_waitcnt vmcnt(8)" ::: "memory");   // tile0's 8 landed
    __builtin_amdgcn_s_barrier();

    for (int kt = 0; kt < 102; kt += 2) {
        ROUND(sA[0], sB[0], 0, 0,  kt < 100);
        ROUND(sA[1], sB[1], 1, 64, kt < 99);
        pA += 128; pB0 += 128; pB1 += 128; pB2 += 128; pB3 += 128;
    }

    // ---- epilogue: 32x32 C/D: col=lane&31, row=(r&3)+8*(r>>2)+4*g ----
#define EPI(ACC, COL) {                                                      \
    const bool val   = (COL) < GN;                                           \
    const bool wr_ok = (COL) < KP;                                           \
    const float bv = val ? bias[COL] : 0.f;                                  \
    if (wr_ok) { _Pragma("unroll")                                           \
        for (int f = 0; f < 4; ++f) { _Pragma("unroll")                      \
            for (int r = 0; r < 16; ++r) {                                   \
                const long row = tile_m + wr * 128 + f * 32                  \
                               + (r & 3) + 8 * (r >> 2) + 4 * g;             \
                float v = ACC[f][r] + bv;                                    \
                v = v > 0.f ? v : 0.f;                                       \
                C[row * (long)KP + (COL)] = val ? (_Float16)v : (_Float16)0.f; \
            } } } }

    const long colS = tile_n + bS + fr32;
    const long colO = tile_n + bO + fr32;
    EPI(accS, colS);
    EPI(accO, colO);

#undef GLD
#undef STAGE_A4
#undef STAGE_B4
#undef LDA
#undef LDBF
#undef MMAP
#undef ROUND
#undef EPI
}

// ---------------------------------------------------------------------------
// Final projection: out[b,o] = sum_k F[b,k]*wo[o,k] + bo[o].
// ---------------------------------------------------------------------------
__global__ __launch_bounds__(256) void final_out(
    const _Float16* __restrict__ F, const float* __restrict__ wo,
    const float* __restrict__ bo, float* __restrict__ out)
{
    __shared__ float red[4][8];
    const long b   = blockIdx.x;
    const int tid  = threadIdx.x;
    const int lane = tid & 63;
    const int wave = tid >> 6;
    float acc[5] = {0.f, 0.f, 0.f, 0.f, 0.f};
    const _Float16* f = F + b * KP;

    const int c1 = (wave + 1) * 402;
    for (int c = wave * 402 + lane; c < c1; c += 64) {
        const int k = c << 2;
        v4h f4 = *(const v4h*)(f + k);
        const float f0 = (float)f4[0], f1 = (float)f4[1];
        const float f2 = (float)f4[2], f3 = (float)f4[3];
        #pragma unroll
        for (int o = 0; o < 5; ++o) {
            const float4 w4 = *(const float4*)(wo + o * GK + k);
            acc[o] += f0 * w4.x + f1 * w4.y + f2 * w4.z + f3 * w4.w;
        }
    }
    #pragma unroll
    for (int o = 0; o < 5; ++o) {
        #pragma unroll
        for (int off = 32; off > 0; off >>= 1) acc[o] += __shfl_down(acc[o], off, 64);
    }
    if (lane == 0) {
        #pragma unroll
        for (int o = 0; o < 5; ++o) red[wave][o] = acc[o];
    }
    __syncthreads();
    if (tid < 5)
        out[b * 5 + tid] = red[0][tid] + red[1][tid] + red[2][tid] + red[3][tid] + bo[tid];
}

// ---------------------------------------------------------------------------
extern "C" void kernel_launch(void* const* d_in, const int* in_sizes, int n_in,
                              void* d_out, int out_size, void* d_ws, size_t ws_size,
                              hipStream_t stream)
{
    const float* x  = (const float*)d_in[0];
    const float* w1 = (const float*)d_in[1];
    const float* b1 = (const float*)d_in[2];
    const float* w2 = (const float*)d_in[3];
    const float* b2 = (const float*)d_in[4];
    const float* wl = (const float*)d_in[5];
    const float* bl = (const float*)d_in[6];
    const float* wo = (const float*)d_in[7];
    const float* bo = (const float*)d_in[8];
    float* out = (float*)d_out;

    char* ws = (char*)d_ws;
    _Float16* Wh = (_Float16*)ws;                                   // 6432*6528*2 = 83,976,192 B
    _Float16* F0 = (_Float16*)(ws + 83976192);                      // 2048*6528*2 = 26,738,688 B
    _Float16* F1 = (_Float16*)(ws + 83976192 + 26738688);

    convert_w<<<dim3(7, GN), 256, 0, stream>>>(wl, Wh);
    conv_feat<<<GM, 256, 0, stream>>>(x, w1, b1, w2, b2, F0);
    gemm8<<<208, 512, 0, stream>>>(F0, Wh, bl, F1);
    gemm8<<<208, 512, 0, stream>>>(F1, Wh, bl, F0);
    gemm8<<<208, 512, 0, stream>>>(F0, Wh, bl, F1);
    gemm8<<<208, 512, 0, stream>>>(F1, Wh, bl, F0);
    final_out<<<GM, 256, 0, stream>>>(F0, wo, bo, out);
}